// Round 1
// baseline (1024.830 us; speedup 1.0000x reference)
//
#include <hip/hip_runtime.h>

// Problem constants (from reference): T=2048, B=16, D=1024
#define T_DIM 2048
#define B_DIM 16
#define D_DIM 1024
#define M_DIM (T_DIM * B_DIM)   // 32768 rows of the projection GEMM
#define K_DIM D_DIM             // 1024
#define N_DIM D_DIM             // 1024
#define BD    (B_DIM * D_DIM)   // 16384 independent scan channels

// ---------------- GEMM: proj = x @ W^T + b ----------------
// x: [M, K] row-major (T*B rows, D inner), W: [N, K] row-major (e rows, d inner)
// 128x128 tile, BK=16, 256 threads, 8x8 micro-tile per thread. fp32 VALU.
#define BM 128
#define BN 128
#define BK 16
#define LDS_PAD 4

__global__ __launch_bounds__(256) void gemm_proj(const float* __restrict__ x,
                                                 const float* __restrict__ W,
                                                 const float* __restrict__ bias,
                                                 float* __restrict__ proj) {
    __shared__ float As[BK][BM + LDS_PAD];  // stored transposed: As[k][row]
    __shared__ float Bs[BK][BN + LDS_PAD];  // stored transposed: Bs[k][col]

    const int bx = blockIdx.x;   // N tile index, 0..7
    const int by = blockIdx.y;   // M tile index, 0..255
    const int tid = threadIdx.x;
    const int tx = tid & 15;     // 0..15 -> output cols tx*8..tx*8+7
    const int ty = tid >> 4;     // 0..15 -> output rows ty*8..ty*8+7
    const int row0 = by * BM;
    const int col0 = bx * BN;

    float acc[8][8];
#pragma unroll
    for (int i = 0; i < 8; ++i)
#pragma unroll
        for (int j = 0; j < 8; ++j) acc[i][j] = 0.f;

    for (int kt = 0; kt < K_DIM; kt += BK) {
        // Stage: 128x16 floats per tile = 512 float4; 256 threads x 2 each.
        float4 av[2], bv[2];
#pragma unroll
        for (int i = 0; i < 2; ++i) {
            const int fi = tid + i * 256;       // coalesced: lane-consecutive float4
            const int r  = fi >> 2;             // 0..127
            const int c4 = (fi & 3) << 2;       // 0,4,8,12
            av[i] = *(const float4*)&x[(size_t)(row0 + r) * K_DIM + kt + c4];
            bv[i] = *(const float4*)&W[(size_t)(col0 + r) * K_DIM + kt + c4];
        }
        __syncthreads();   // previous tile's compute done before overwrite
#pragma unroll
        for (int i = 0; i < 2; ++i) {
            const int fi = tid + i * 256;
            const int r  = fi >> 2;
            const int c4 = (fi & 3) << 2;
            As[c4 + 0][r] = av[i].x; As[c4 + 1][r] = av[i].y;
            As[c4 + 2][r] = av[i].z; As[c4 + 3][r] = av[i].w;
            Bs[c4 + 0][r] = bv[i].x; Bs[c4 + 1][r] = bv[i].y;
            Bs[c4 + 2][r] = bv[i].z; Bs[c4 + 3][r] = bv[i].w;
        }
        __syncthreads();
#pragma unroll
        for (int k = 0; k < BK; ++k) {
            float a[8], bb[8];
            *(float4*)&a[0]  = *(const float4*)&As[k][ty * 8];
            *(float4*)&a[4]  = *(const float4*)&As[k][ty * 8 + 4];
            *(float4*)&bb[0] = *(const float4*)&Bs[k][tx * 8];
            *(float4*)&bb[4] = *(const float4*)&Bs[k][tx * 8 + 4];
#pragma unroll
            for (int i = 0; i < 8; ++i)
#pragma unroll
                for (int j = 0; j < 8; ++j)
                    acc[i][j] = fmaf(a[i], bb[j], acc[i][j]);
        }
    }

    // Epilogue: add bias, store coalesced float4 pairs.
    const float4 bz0 = *(const float4*)&bias[col0 + tx * 8];
    const float4 bz1 = *(const float4*)&bias[col0 + tx * 8 + 4];
#pragma unroll
    for (int i = 0; i < 8; ++i) {
        const size_t r = (size_t)(row0 + ty * 8 + i);
        float4 o0, o1;
        o0.x = acc[i][0] + bz0.x; o0.y = acc[i][1] + bz0.y;
        o0.z = acc[i][2] + bz0.z; o0.w = acc[i][3] + bz0.w;
        o1.x = acc[i][4] + bz1.x; o1.y = acc[i][5] + bz1.y;
        o1.z = acc[i][6] + bz1.z; o1.w = acc[i][7] + bz1.w;
        *(float4*)&proj[r * N_DIM + col0 + tx * 8]     = o0;
        *(float4*)&proj[r * N_DIM + col0 + tx * 8 + 4] = o1;
    }
}

// ---------------- Scan: per-(b,d) independent linear recurrence ----------------
// po holds proj on entry; each thread reads proj[t,idx], overwrites it in place
// with out[t,idx], and writes h[t+1,idx]. h[0,:]=0.
__global__ __launch_bounds__(64) void scan_fused(float* __restrict__ po,
                                                 float* __restrict__ h_out) {
    const int idx = blockIdx.x * 64 + threadIdx.x;
    float h = 0.f;
    h_out[idx] = 0.f;                      // h0 row
    size_t off = (size_t)idx;
#pragma unroll 4
    for (int t = 0; t < T_DIM; ++t) {
        const float p   = po[off];
        const float ep  = __expf(-p);                       // e^-p
        const float alpha = __builtin_amdgcn_rcpf(1.f + ep);  // sigmoid(p)
        const float beta  = ep * alpha;                       // 1 - sigmoid(p)
        const float ep2 = ep * ep;                            // e^-2p
        const float th  = (1.f - ep2) * __builtin_amdgcn_rcpf(1.f + ep2); // tanh(p)
        h = fmaf(alpha, h, beta * th);
        const float sh = __builtin_amdgcn_rcpf(1.f + __expf(-h));  // sigmoid(h)
        po[off] = h * h * sh;              // h * silu(h)
        h_out[off + BD] = h;
        off += BD;
    }
}

extern "C" void kernel_launch(void* const* d_in, const int* in_sizes, int n_in,
                              void* d_out, int out_size, void* d_ws, size_t ws_size,
                              hipStream_t stream) {
    const float* x = (const float*)d_in[0];   // [T,B,D]
    const float* W = (const float*)d_in[1];   // [D,D]
    const float* b = (const float*)d_in[2];   // [D]
    float* out = (float*)d_out;                               // outputs region (also proj scratch)
    float* h   = out + (size_t)T_DIM * B_DIM * D_DIM;          // h region, (T+1)*B*D

    dim3 grid(N_DIM / BN, M_DIM / BM);        // 8 x 256
    gemm_proj<<<grid, 256, 0, stream>>>(x, W, b, out);
    scan_fused<<<BD / 64, 64, 0, stream>>>(out, h);
}

// Round 2
// 425.770 us; speedup vs baseline: 2.4070x; 2.4070x over previous
//
#include <hip/hip_runtime.h>

// Problem constants: T=2048, B=16, D=1024
#define T_DIM 2048
#define B_DIM 16
#define D_DIM 1024
#define M_DIM (T_DIM * B_DIM)   // 32768
#define K_DIM D_DIM             // 1024
#define N_DIM D_DIM             // 1024
#define BD    (B_DIM * D_DIM)   // 16384 scan channels

typedef __attribute__((ext_vector_type(8))) short  bf16x8;
typedef __attribute__((ext_vector_type(16))) float f32x16;

__device__ __forceinline__ ushort f2bf_rne(float f) {
    unsigned u = __builtin_bit_cast(unsigned, f);
    u += 0x7FFFu + ((u >> 16) & 1u);
    return (ushort)(u >> 16);
}
__device__ __forceinline__ float bf2f(ushort h) {
    unsigned u = ((unsigned)h) << 16;
    return __builtin_bit_cast(float, u);
}

// ---------------- GEMM: proj = x @ W^T + b  (split bf16 MFMA) ----------------
// x: [M,K] row-major, W: [N,K] row-major. Tile 128x128, BK=32, 256 threads,
// 4 waves each computing 64x64 via 2x2 frags of v_mfma_f32_32x32x16_bf16.
// acc += Ah*Bh + Ah*Bl + Al*Bh  (lo*lo dropped, ~2^-18 relative).
#define BK 32

__global__ __launch_bounds__(256) void gemm_proj_mfma(const float* __restrict__ x,
                                                      const float* __restrict__ W,
                                                      const float* __restrict__ bias,
                                                      float* __restrict__ proj) {
    // [k-chunk(8)][row][k-in-chunk] : fragment ds_read_b128 is conflict-free
    __shared__ ushort Ah[4][128][8];
    __shared__ ushort Al[4][128][8];
    __shared__ ushort Bh[4][128][8];
    __shared__ ushort Bl[4][128][8];

    // XCD-aware swizzle: nwg=2048, 8 XCDs, 256 blocks each; within an XCD,
    // ids run (by,bx) so the 8 bx-blocks sharing an x-slab co-reside.
    const int bid = (int)blockIdx.x;
    const int swz = (bid & 7) * 256 + (bid >> 3);
    const int bx = swz & 7;        // N tile 0..7
    const int by = swz >> 3;       // M tile 0..255
    const int row0 = by * 128;
    const int col0 = bx * 128;
    const int tid  = (int)threadIdx.x;
    const int lane = tid & 63;
    const int wave = tid >> 6;
    const int wm = (wave >> 1) * 64;
    const int wn = (wave & 1) * 64;

    f32x16 acc[2][2];
#pragma unroll
    for (int m = 0; m < 2; ++m)
#pragma unroll
        for (int n = 0; n < 2; ++n)
#pragma unroll
            for (int r = 0; r < 16; ++r) acc[m][n][r] = 0.f;

    const float* xg = x + (size_t)row0 * K_DIM;
    const float* wg = W + (size_t)col0 * K_DIM;

    // Staging: 128 rows x 32 k fp32 = 1024 float4 per operand; 4 per thread.
    float4 pa[4], pb[4];
#pragma unroll
    for (int i = 0; i < 4; ++i) {
        const int fi = tid + i * 256;
        const int r  = fi >> 3;
        const int c4 = (fi & 7) << 2;
        pa[i] = *(const float4*)&xg[(size_t)r * K_DIM + c4];
        pb[i] = *(const float4*)&wg[(size_t)r * K_DIM + c4];
    }

    for (int kt = 0; kt < K_DIM; kt += BK) {
        __syncthreads();   // previous tile's compute done
#pragma unroll
        for (int i = 0; i < 4; ++i) {
            const int fi = tid + i * 256;
            const int r  = fi >> 3;
            const int c4 = (fi & 7) << 2;
            const int ch = c4 >> 3;
            const int co = c4 & 4;
            const float f[4] = {pa[i].x, pa[i].y, pa[i].z, pa[i].w};
            const float g[4] = {pb[i].x, pb[i].y, pb[i].z, pb[i].w};
            ushort ah[4], al[4], bh[4], bl[4];
#pragma unroll
            for (int j = 0; j < 4; ++j) {
                ah[j] = f2bf_rne(f[j]); al[j] = f2bf_rne(f[j] - bf2f(ah[j]));
                bh[j] = f2bf_rne(g[j]); bl[j] = f2bf_rne(g[j] - bf2f(bh[j]));
            }
            *(ushort4*)&Ah[ch][r][co] = make_ushort4(ah[0], ah[1], ah[2], ah[3]);
            *(ushort4*)&Al[ch][r][co] = make_ushort4(al[0], al[1], al[2], al[3]);
            *(ushort4*)&Bh[ch][r][co] = make_ushort4(bh[0], bh[1], bh[2], bh[3]);
            *(ushort4*)&Bl[ch][r][co] = make_ushort4(bl[0], bl[1], bl[2], bl[3]);
        }
        if (kt + BK < K_DIM) {   // prefetch next tile while this one computes
#pragma unroll
            for (int i = 0; i < 4; ++i) {
                const int fi = tid + i * 256;
                const int r  = fi >> 3;
                const int c4 = (fi & 7) << 2;
                pa[i] = *(const float4*)&xg[(size_t)r * K_DIM + kt + BK + c4];
                pb[i] = *(const float4*)&wg[(size_t)r * K_DIM + kt + BK + c4];
            }
        }
        __syncthreads();
#pragma unroll
        for (int kk = 0; kk < 2; ++kk) {
            const int ch = kk * 2 + (lane >> 5);
            const int ar = wm + (lane & 31);
            const int br = wn + (lane & 31);
            bf16x8 fah[2], fal[2], fbh[2], fbl[2];
#pragma unroll
            for (int m = 0; m < 2; ++m) {
                fah[m] = *(const bf16x8*)&Ah[ch][ar + m * 32][0];
                fal[m] = *(const bf16x8*)&Al[ch][ar + m * 32][0];
            }
#pragma unroll
            for (int n = 0; n < 2; ++n) {
                fbh[n] = *(const bf16x8*)&Bh[ch][br + n * 32][0];
                fbl[n] = *(const bf16x8*)&Bl[ch][br + n * 32][0];
            }
#pragma unroll
            for (int m = 0; m < 2; ++m)
#pragma unroll
                for (int n = 0; n < 2; ++n) {
                    acc[m][n] = __builtin_amdgcn_mfma_f32_32x32x16_bf16(fah[m], fbh[n], acc[m][n], 0, 0, 0);
                    acc[m][n] = __builtin_amdgcn_mfma_f32_32x32x16_bf16(fah[m], fbl[n], acc[m][n], 0, 0, 0);
                    acc[m][n] = __builtin_amdgcn_mfma_f32_32x32x16_bf16(fal[m], fbh[n], acc[m][n], 0, 0, 0);
                }
        }
    }

    // Epilogue: C/D layout col=lane&31, row=(reg&3)+8*(reg>>2)+4*(lane>>5)
#pragma unroll
    for (int n = 0; n < 2; ++n) {
        const int col = col0 + wn + n * 32 + (lane & 31);
        const float bz = bias[col];
#pragma unroll
        for (int m = 0; m < 2; ++m) {
            const int rbase = row0 + wm + m * 32 + 4 * (lane >> 5);
#pragma unroll
            for (int r = 0; r < 16; ++r) {
                const int row = rbase + (r & 3) + 8 * (r >> 2);
                proj[(size_t)row * N_DIM + col] = acc[m][n][r] + bz;
            }
        }
    }
}

// ---------------- Scan: per-(b,d) recurrence, depth-16 prefetch pipeline ----------------
__global__ __launch_bounds__(64) void scan_fused(float* __restrict__ po,
                                                 float* __restrict__ h_out) {
    const int idx = (int)blockIdx.x * 64 + (int)threadIdx.x;
    float h = 0.f;
    h_out[idx] = 0.f;                       // h0 row
    const size_t base = (size_t)idx;

    float cA[8], cB[8];
#pragma unroll
    for (int j = 0; j < 8; ++j) cA[j] = po[base + (size_t)j * BD];
#pragma unroll
    for (int j = 0; j < 8; ++j) cB[j] = po[base + (size_t)(8 + j) * BD];

    size_t off = base;
    for (int g = 0; g < T_DIM / 8; ++g) {
        float cN[8];
        if (g + 2 < T_DIM / 8) {
            const size_t loff = base + (size_t)(g + 2) * 8 * BD;
#pragma unroll
            for (int j = 0; j < 8; ++j) cN[j] = po[loff + (size_t)j * BD];
        }
#pragma unroll
        for (int j = 0; j < 8; ++j) {
            const float p     = cA[j];
            const float ep    = __expf(-p);
            const float alpha = __builtin_amdgcn_rcpf(1.f + ep);   // sigmoid(p)
            const float beta  = ep * alpha;                         // 1-sigmoid(p)
            const float ep2   = ep * ep;
            const float th    = (1.f - ep2) * __builtin_amdgcn_rcpf(1.f + ep2); // tanh(p)
            h = fmaf(alpha, h, beta * th);
            const float sh = __builtin_amdgcn_rcpf(1.f + __expf(-h));
            po[off]         = h * h * sh;   // h * silu(h)
            h_out[off + BD] = h;
            off += BD;
        }
#pragma unroll
        for (int j = 0; j < 8; ++j) { cA[j] = cB[j]; cB[j] = cN[j]; }
    }
}

extern "C" void kernel_launch(void* const* d_in, const int* in_sizes, int n_in,
                              void* d_out, int out_size, void* d_ws, size_t ws_size,
                              hipStream_t stream) {
    const float* x = (const float*)d_in[0];
    const float* W = (const float*)d_in[1];
    const float* b = (const float*)d_in[2];
    float* out = (float*)d_out;                               // outputs / proj scratch
    float* h   = out + (size_t)T_DIM * B_DIM * D_DIM;          // h region

    gemm_proj_mfma<<<(M_DIM / 128) * (N_DIM / 128), 256, 0, stream>>>(x, W, b, out);
    scan_fused<<<BD / 64, 64, 0, stream>>>(out, h);
}

// Round 3
// 418.980 us; speedup vs baseline: 2.4460x; 1.0162x over previous
//
#include <hip/hip_runtime.h>

// T=2048, B=16, D=1024
#define T_DIM 2048
#define B_DIM 16
#define D_DIM 1024
#define M_DIM (T_DIM * B_DIM)   // 32768
#define K_DIM D_DIM
#define N_DIM D_DIM
#define BD    (B_DIM * D_DIM)   // 16384 scan channels

typedef _Float16 f16;
typedef __attribute__((ext_vector_type(8)))  _Float16 f16x8;
typedef __attribute__((ext_vector_type(16))) float    f32x16;

#define GLD16(g, l) __builtin_amdgcn_global_load_lds(                        \
    (const __attribute__((address_space(1))) unsigned*)(g),                  \
    (__attribute__((address_space(3))) unsigned*)(l), 16, 0, 0)

// Tiled fp16 layout: per (block,kt) tile of 128 rows x 32 k:
//   ushort idx = ((kk*2 + khalf)*128 + row)*8 + j   (k = kt*32 + kk*16 + khalf*8 + j)
// Tile = 4096 ushorts = 8192 B, tiles consecutive: base = (blk*32 + kt)*4096 ushorts.

// ---------- pre-pass 1: x fp32 -> Xf fp16 (tiled) ----------
__global__ __launch_bounds__(256) void convert_x(const float* __restrict__ x,
                                                 ushort* __restrict__ Xf) {
    __shared__ ushort tile[4096];
    const int b  = (int)blockIdx.x;      // 8192 blocks
    const int br = b >> 5;               // 0..255 (128-row block)
    const int kt = b & 31;               // 0..31
    const int tid = (int)threadIdx.x;
#pragma unroll
    for (int i = 0; i < 4; ++i) {
        const int fi  = tid + i * 256;   // 0..1023
        const int row = fi >> 3;
        const int kq  = fi & 7;          // float4 index within the 32-k row
        const float4 v = *(const float4*)&x[(size_t)(br * 128 + row) * K_DIM + kt * 32 + kq * 4];
        ushort4 u;
        u.x = __builtin_bit_cast(unsigned short, (f16)v.x);
        u.y = __builtin_bit_cast(unsigned short, (f16)v.y);
        u.z = __builtin_bit_cast(unsigned short, (f16)v.z);
        u.w = __builtin_bit_cast(unsigned short, (f16)v.w);
        const int idx = (((kq >> 2) * 2 + ((kq >> 1) & 1)) * 128 + row) * 8 + (kq & 1) * 4;
        *(ushort4*)&tile[idx] = u;
    }
    __syncthreads();
    const uint4* s = (const uint4*)tile;
    uint4* d = (uint4*)(Xf + (size_t)(br * 32 + kt) * 4096);
    d[tid] = s[tid];
    d[tid + 256] = s[tid + 256];
}

// ---------- pre-pass 2: W fp32 -> Wh + Wl*2048 fp16 (tiled) ----------
__global__ __launch_bounds__(256) void convert_w(const float* __restrict__ W,
                                                 ushort* __restrict__ Wh,
                                                 ushort* __restrict__ Wl) {
    __shared__ ushort th[4096];
    __shared__ ushort tl[4096];
    const int b  = (int)blockIdx.x;      // 256 blocks
    const int bc = b >> 5;               // 0..7 (128-col block)
    const int kt = b & 31;
    const int tid = (int)threadIdx.x;
#pragma unroll
    for (int i = 0; i < 4; ++i) {
        const int fi  = tid + i * 256;
        const int col = fi >> 3;
        const int kq  = fi & 7;
        const float4 v = *(const float4*)&W[(size_t)(bc * 128 + col) * K_DIM + kt * 32 + kq * 4];
        const float f[4] = {v.x, v.y, v.z, v.w};
        ushort4 uh, ul;
        unsigned short* ph = (unsigned short*)&uh;
        unsigned short* pl = (unsigned short*)&ul;
#pragma unroll
        for (int j = 0; j < 4; ++j) {
            const f16 hh = (f16)f[j];
            const float r = f[j] - (float)hh;       // residual, |r| <= ulp/2
            const f16 hl = (f16)(r * 2048.f);       // scaled into fp16 normal range
            ph[j] = __builtin_bit_cast(unsigned short, hh);
            pl[j] = __builtin_bit_cast(unsigned short, hl);
        }
        const int idx = (((kq >> 2) * 2 + ((kq >> 1) & 1)) * 128 + col) * 8 + (kq & 1) * 4;
        *(ushort4*)&th[idx] = uh;
        *(ushort4*)&tl[idx] = ul;
    }
    __syncthreads();
    const uint4* sh = (const uint4*)th;
    const uint4* sl = (const uint4*)tl;
    uint4* dh = (uint4*)(Wh + (size_t)(bc * 32 + kt) * 4096);
    uint4* dl = (uint4*)(Wl + (size_t)(bc * 32 + kt) * 4096);
    dh[tid] = sh[tid]; dh[tid + 256] = sh[tid + 256];
    dl[tid] = sl[tid]; dl[tid + 256] = sl[tid + 256];
}

// ---------- GEMM: proj = Xf*(Wh + Wl/2048) + b ----------
// 128x128 tile, BK=32, 4 waves (2x2), each 64x64 via 2x2 frags of mfma_f32_32x32x16_f16.
__global__ __launch_bounds__(256) void gemm_proj_f16(const ushort* __restrict__ Xf,
                                                     const ushort* __restrict__ Wh,
                                                     const ushort* __restrict__ Wl,
                                                     const float* __restrict__ bias,
                                                     float* __restrict__ proj) {
    __shared__ ushort lA[4096];
    __shared__ ushort lBh[4096];
    __shared__ ushort lBl[4096];

    const int bid = (int)blockIdx.x;                 // 2048
    const int swz = (bid & 7) * 256 + (bid >> 3);    // XCD swizzle: same-A blocks co-XCD
    const int bc  = swz & 7;
    const int br  = swz >> 3;
    const int tid  = (int)threadIdx.x;
    const int lane = tid & 63;
    const int wave = tid >> 6;
    const int wm = (wave >> 1) * 64;
    const int wn = (wave & 1) * 64;
    const int kh  = lane >> 5;
    const int r32 = lane & 31;

    f32x16 accH[2][2], accL[2][2];
#pragma unroll
    for (int m = 0; m < 2; ++m)
#pragma unroll
        for (int n = 0; n < 2; ++n)
#pragma unroll
            for (int r = 0; r < 16; ++r) { accH[m][n][r] = 0.f; accL[m][n][r] = 0.f; }

    const char* aG  = (const char*)Xf + (size_t)br * 32 * 8192;
    const char* bhG = (const char*)Wh + (size_t)bc * 32 * 8192;
    const char* blG = (const char*)Wl + (size_t)bc * 32 * 8192;

    // frag base offsets (ushort index), kk adds 2048, m/n add 256
    const int aoff = (kh * 128 + wm + r32) * 8;
    const int boff = (kh * 128 + wn + r32) * 8;

    for (int kt = 0; kt < 32; ++kt) {
        __syncthreads();   // previous compute's ds_reads done before overwrite
        const size_t tb = (size_t)kt * 8192;
        GLD16(aG  + tb + (size_t)tid * 16,         (char*)lA  + tid * 16);
        GLD16(aG  + tb + (size_t)(tid + 256) * 16, (char*)lA  + (tid + 256) * 16);
        GLD16(bhG + tb + (size_t)tid * 16,         (char*)lBh + tid * 16);
        GLD16(bhG + tb + (size_t)(tid + 256) * 16, (char*)lBh + (tid + 256) * 16);
        GLD16(blG + tb + (size_t)tid * 16,         (char*)lBl + tid * 16);
        GLD16(blG + tb + (size_t)(tid + 256) * 16, (char*)lBl + (tid + 256) * 16);
        __syncthreads();   // vmcnt(0) drain: tile resident
#pragma unroll
        for (int kk = 0; kk < 2; ++kk) {
            f16x8 fa[2], fbh[2], fbl[2];
#pragma unroll
            for (int m = 0; m < 2; ++m)
                fa[m] = *(const f16x8*)&lA[aoff + kk * 2048 + m * 256];
#pragma unroll
            for (int n = 0; n < 2; ++n) {
                fbh[n] = *(const f16x8*)&lBh[boff + kk * 2048 + n * 256];
                fbl[n] = *(const f16x8*)&lBl[boff + kk * 2048 + n * 256];
            }
#pragma unroll
            for (int m = 0; m < 2; ++m)
#pragma unroll
                for (int n = 0; n < 2; ++n) {
                    accH[m][n] = __builtin_amdgcn_mfma_f32_32x32x16_f16(fa[m], fbh[n], accH[m][n], 0, 0, 0);
                    accL[m][n] = __builtin_amdgcn_mfma_f32_32x32x16_f16(fa[m], fbl[n], accL[m][n], 0, 0, 0);
                }
        }
    }

    // C/D layout: col = lane&31, row = (r&3) + 8*(r>>2) + 4*(lane>>5)  (verified round 2)
#pragma unroll
    for (int n = 0; n < 2; ++n) {
        const int col = bc * 128 + wn + n * 32 + r32;
        const float bz = bias[col];
#pragma unroll
        for (int m = 0; m < 2; ++m) {
            const int rbase = br * 128 + wm + m * 32 + 4 * kh;
#pragma unroll
            for (int r = 0; r < 16; ++r) {
                const int row = rbase + (r & 3) + 8 * (r >> 2);
                proj[(size_t)row * N_DIM + col] =
                    accH[m][n][r] + accL[m][n][r] * (1.f / 2048.f) + bz;
            }
        }
    }
}

// ---------- Scan: per-(b,d) recurrence, depth-24 prefetch ----------
__global__ __launch_bounds__(64) void scan_fused(float* __restrict__ po,
                                                 float* __restrict__ h_out) {
    const int idx = (int)blockIdx.x * 64 + (int)threadIdx.x;
    float h = 0.f;
    h_out[idx] = 0.f;                       // h0 row
    const size_t base = (size_t)idx;

    float cA[8], cB[8], cC[8];
#pragma unroll
    for (int j = 0; j < 8; ++j) cA[j] = po[base + (size_t)j * BD];
#pragma unroll
    for (int j = 0; j < 8; ++j) cB[j] = po[base + (size_t)(8 + j) * BD];
#pragma unroll
    for (int j = 0; j < 8; ++j) cC[j] = po[base + (size_t)(16 + j) * BD];

    size_t off = base;
    for (int g = 0; g < T_DIM / 8; ++g) {
        float cN[8];
        if (g + 3 < T_DIM / 8) {
            const size_t loff = base + (size_t)(g + 3) * 8 * BD;
#pragma unroll
            for (int j = 0; j < 8; ++j) cN[j] = po[loff + (size_t)j * BD];
        }
#pragma unroll
        for (int j = 0; j < 8; ++j) {
            const float p     = cA[j];
            const float ep    = __expf(-p);
            const float alpha = __builtin_amdgcn_rcpf(1.f + ep);    // sigmoid(p)
            const float beta  = ep * alpha;                          // 1-sigmoid(p)
            const float ep2   = ep * ep;
            const float th    = (1.f - ep2) * __builtin_amdgcn_rcpf(1.f + ep2); // tanh(p)
            h = fmaf(alpha, h, beta * th);
            const float sh = __builtin_amdgcn_rcpf(1.f + __expf(-h));
            po[off]         = h * h * sh;   // h * silu(h)
            h_out[off + BD] = h;
            off += BD;
        }
#pragma unroll
        for (int j = 0; j < 8; ++j) { cA[j] = cB[j]; cB[j] = cC[j]; cC[j] = cN[j]; }
    }
}

extern "C" void kernel_launch(void* const* d_in, const int* in_sizes, int n_in,
                              void* d_out, int out_size, void* d_ws, size_t ws_size,
                              hipStream_t stream) {
    const float* x = (const float*)d_in[0];
    const float* W = (const float*)d_in[1];
    const float* b = (const float*)d_in[2];
    float* out = (float*)d_out;                                // outputs / proj (128 MB)
    float* h   = out + (size_t)T_DIM * B_DIM * D_DIM;          // h region (134.3 MB)

    // Scratch inside the h region (consumed by GEMM before scan overwrites it):
    ushort* Xf = (ushort*)h;                                   // 64 MB
    ushort* Wh = Xf + (size_t)M_DIM * K_DIM;                   // 2 MB
    ushort* Wl = Wh + (size_t)N_DIM * K_DIM;                   // 2 MB

    convert_x<<<8192, 256, 0, stream>>>(x, Xf);
    convert_w<<<256, 256, 0, stream>>>(W, Wh, Wl);
    gemm_proj_f16<<<2048, 256, 0, stream>>>(Xf, Wh, Wl, b, out);
    scan_fused<<<BD / 64, 64, 0, stream>>>(out, h);
}

// Round 4
// 335.994 us; speedup vs baseline: 3.0501x; 1.2470x over previous
//
#include <hip/hip_runtime.h>

// T=2048, B=16, D=1024
#define T_DIM 2048
#define B_DIM 16
#define D_DIM 1024
#define M_DIM (T_DIM * B_DIM)   // 32768
#define K_DIM D_DIM
#define N_DIM D_DIM
#define BD    (B_DIM * D_DIM)   // 16384 scan channels

typedef _Float16 f16;
typedef __attribute__((ext_vector_type(8)))  _Float16 f16x8;
typedef __attribute__((ext_vector_type(16))) float    f32x16;

#define GLD16(g, l) __builtin_amdgcn_global_load_lds(                        \
    (const __attribute__((address_space(1))) unsigned*)(g),                  \
    (__attribute__((address_space(3))) unsigned*)(l), 16, 0, 0)

#define CFENCE asm volatile("" ::: "memory")
#define BARRIER do { CFENCE; __builtin_amdgcn_s_barrier(); CFENCE; } while (0)

// Tiled fp16 layouts (k-plane c = k>>3, 8 k per plane):
//  A tile (per br 0..127, kt 0..15): [c 8][row 256][8]  = 16384 ushort = 32 KiB
//  B tile (per bc 0..7,   kt 0..15): [c 8][col 128][8]  =  8192 ushort = 16 KiB

// ---------- pre-pass 1: x fp32 -> Xf fp16 (A-tiled) ----------
__global__ __launch_bounds__(256) void convert_x(const float* __restrict__ x,
                                                 ushort* __restrict__ Xf) {
    __shared__ ushort tile[16384];
    const int b   = (int)blockIdx.x;     // 2048 = 128 br x 16 kt
    const int br  = b >> 4;
    const int kt  = b & 15;
    const int tid = (int)threadIdx.x;
#pragma unroll
    for (int i = 0; i < 16; ++i) {
        const int fi  = tid + i * 256;   // 0..4095
        const int row = fi >> 4;         // 0..255
        const int kq  = fi & 15;         // float4 index in 64-k row
        const float4 v = *(const float4*)&x[(size_t)(br * 256 + row) * K_DIM + kt * 64 + kq * 4];
        ushort4 u;
        u.x = __builtin_bit_cast(unsigned short, (f16)v.x);
        u.y = __builtin_bit_cast(unsigned short, (f16)v.y);
        u.z = __builtin_bit_cast(unsigned short, (f16)v.z);
        u.w = __builtin_bit_cast(unsigned short, (f16)v.w);
        const int idx = ((kq >> 1) * 256 + row) * 8 + (kq & 1) * 4;
        *(ushort4*)&tile[idx] = u;
    }
    __syncthreads();
    const uint4* s = (const uint4*)tile;                 // 2048 x 16B
    uint4* d = (uint4*)(Xf + (size_t)b * 16384);
#pragma unroll
    for (int i = 0; i < 8; ++i) d[tid + i * 256] = s[tid + i * 256];
}

// ---------- pre-pass 2: W fp32 -> Wh + Wl*2048 fp16 (B-tiled) ----------
__global__ __launch_bounds__(256) void convert_w(const float* __restrict__ W,
                                                 ushort* __restrict__ Wh,
                                                 ushort* __restrict__ Wl) {
    __shared__ ushort th[8192];
    __shared__ ushort tl[8192];
    const int b   = (int)blockIdx.x;     // 128 = 8 bc x 16 kt
    const int bc  = b >> 4;
    const int kt  = b & 15;
    const int tid = (int)threadIdx.x;
#pragma unroll
    for (int i = 0; i < 8; ++i) {
        const int fi  = tid + i * 256;   // 0..2047
        const int col = fi >> 4;         // 0..127
        const int kq  = fi & 15;
        const float4 v = *(const float4*)&W[(size_t)(bc * 128 + col) * K_DIM + kt * 64 + kq * 4];
        const float f[4] = {v.x, v.y, v.z, v.w};
        ushort4 uh, ul;
        unsigned short* ph = (unsigned short*)&uh;
        unsigned short* pl = (unsigned short*)&ul;
#pragma unroll
        for (int j = 0; j < 4; ++j) {
            const f16 hh = (f16)f[j];
            const float r = f[j] - (float)hh;
            const f16 hl = (f16)(r * 2048.f);
            ph[j] = __builtin_bit_cast(unsigned short, hh);
            pl[j] = __builtin_bit_cast(unsigned short, hl);
        }
        const int idx = ((kq >> 1) * 128 + col) * 8 + (kq & 1) * 4;
        *(ushort4*)&th[idx] = uh;
        *(ushort4*)&tl[idx] = ul;
    }
    __syncthreads();
    const uint4* sh = (const uint4*)th;                  // 1024 x 16B
    const uint4* sl = (const uint4*)tl;
    uint4* dh = (uint4*)(Wh + (size_t)b * 8192);
    uint4* dl = (uint4*)(Wl + (size_t)b * 8192);
#pragma unroll
    for (int i = 0; i < 4; ++i) {
        dh[tid + i * 256] = sh[tid + i * 256];
        dl[tid + i * 256] = sl[tid + i * 256];
    }
}

// ---------- GEMM: proj = Xf*(Wh + Wl/2048)^T + b ----------
// 256x128(real)x dual tile, BK=64, 8 waves, double-buffered LDS, counted vmcnt.
__global__ __launch_bounds__(512, 2) void gemm_proj_f16(const ushort* __restrict__ Xf,
                                                        const ushort* __restrict__ Wh,
                                                        const ushort* __restrict__ Wl,
                                                        const float* __restrict__ bias,
                                                        float* __restrict__ proj) {
    __shared__ ushort sA[2][16384];   // 2 x 32 KiB
    __shared__ ushort sBh[2][8192];   // 2 x 16 KiB
    __shared__ ushort sBl[2][8192];   // 2 x 16 KiB

    const int bid = (int)blockIdx.x;                 // 1024 blocks
    const int swz = (bid & 7) * 128 + (bid >> 3);    // XCD x owns br-slab [x*16, x*16+16)
    const int bc  = swz & 7;
    const int br  = swz >> 3;
    const int tid  = (int)threadIdx.x;
    const int lane = tid & 63;
    const int wid  = tid >> 6;
    const int wr = wid >> 2;         // 0..1 : 128-row half
    const int wc = wid & 3;          // 0..3 : 32-col slice
    const int kh  = lane >> 5;
    const int r32 = lane & 31;

    const char* aG  = (const char*)(Xf + (size_t)br * 16 * 16384);
    const char* bhG = (const char*)(Wh + (size_t)bc * 16 * 8192);
    const char* blG = (const char*)(Wl + (size_t)bc * 16 * 8192);

    f32x16 aH[4], aL[4];
#pragma unroll
    for (int m = 0; m < 4; ++m)
#pragma unroll
        for (int r = 0; r < 16; ++r) { aH[m][r] = 0.f; aL[m][r] = 0.f; }

#define STAGE(t, buf) do {                                                      \
        const size_t ta = (size_t)(t) * 32768;                                  \
        const size_t tb = (size_t)(t) * 16384;                                  \
        GLD16(aG  + ta + tid * 16,         (char*)&sA[buf][0]  + tid * 16);     \
        GLD16(aG  + ta + tid * 16 + 8192,  (char*)&sA[buf][0]  + tid * 16 + 8192);  \
        GLD16(aG  + ta + tid * 16 + 16384, (char*)&sA[buf][0]  + tid * 16 + 16384); \
        GLD16(aG  + ta + tid * 16 + 24576, (char*)&sA[buf][0]  + tid * 16 + 24576); \
        GLD16(bhG + tb + tid * 16,         (char*)&sBh[buf][0] + tid * 16);     \
        GLD16(bhG + tb + tid * 16 + 8192,  (char*)&sBh[buf][0] + tid * 16 + 8192);  \
        GLD16(blG + tb + tid * 16,         (char*)&sBl[buf][0] + tid * 16);     \
        GLD16(blG + tb + tid * 16 + 8192,  (char*)&sBl[buf][0] + tid * 16 + 8192);  \
    } while (0)

    STAGE(0, 0);
    STAGE(1, 1);

    for (int t = 0; t < 16; ++t) {
        if (t < 15) asm volatile("s_waitcnt vmcnt(8)" ::: "memory");
        else        asm volatile("s_waitcnt vmcnt(0)" ::: "memory");
        BARRIER;
        const int cur = t & 1;
#pragma unroll
        for (int kk = 0; kk < 4; ++kk) {
            const int c0 = kk * 2 + kh;
            const int ab = (c0 * 256 + wr * 128 + r32) * 8;
            const int bb = (c0 * 128 + wc * 32 + r32) * 8;
            f16x8 fa0 = *(const f16x8*)&sA[cur][ab];
            f16x8 fa1 = *(const f16x8*)&sA[cur][ab + 32 * 8];
            f16x8 fa2 = *(const f16x8*)&sA[cur][ab + 64 * 8];
            f16x8 fa3 = *(const f16x8*)&sA[cur][ab + 96 * 8];
            f16x8 fh  = *(const f16x8*)&sBh[cur][bb];
            f16x8 fl  = *(const f16x8*)&sBl[cur][bb];
            aH[0] = __builtin_amdgcn_mfma_f32_32x32x16_f16(fa0, fh, aH[0], 0, 0, 0);
            aL[0] = __builtin_amdgcn_mfma_f32_32x32x16_f16(fa0, fl, aL[0], 0, 0, 0);
            aH[1] = __builtin_amdgcn_mfma_f32_32x32x16_f16(fa1, fh, aH[1], 0, 0, 0);
            aL[1] = __builtin_amdgcn_mfma_f32_32x32x16_f16(fa1, fl, aL[1], 0, 0, 0);
            aH[2] = __builtin_amdgcn_mfma_f32_32x32x16_f16(fa2, fh, aH[2], 0, 0, 0);
            aL[2] = __builtin_amdgcn_mfma_f32_32x32x16_f16(fa2, fl, aL[2], 0, 0, 0);
            aH[3] = __builtin_amdgcn_mfma_f32_32x32x16_f16(fa3, fh, aH[3], 0, 0, 0);
            aL[3] = __builtin_amdgcn_mfma_f32_32x32x16_f16(fa3, fl, aL[3], 0, 0, 0);
        }
        BARRIER;
        if (t < 14) STAGE(t + 2, cur);
    }
#undef STAGE

    // Epilogue: combine H + L/2048 + bias in registers.
    // C/D layout: col = lane&31, row = (r&3) + 8*(r>>2) + 4*(lane>>5)  (verified r2/r3)
    const int colg = bc * 128 + wc * 32 + r32;
    const float bz = bias[colg];
#pragma unroll
    for (int m = 0; m < 4; ++m) {
        const int rb = br * 256 + wr * 128 + m * 32 + 4 * kh;
#pragma unroll
        for (int r = 0; r < 16; ++r) {
            const int row = rb + (r & 3) + 8 * (r >> 2);
            proj[(size_t)row * N_DIM + colg] = aH[m][r] + aL[m][r] * (1.f / 2048.f) + bz;
        }
    }
}

// ---------- Scan: per-(b,d) recurrence, depth-24 prefetch ----------
__global__ __launch_bounds__(64) void scan_fused(float* __restrict__ po,
                                                 float* __restrict__ h_out) {
    const int idx = (int)blockIdx.x * 64 + (int)threadIdx.x;
    float h = 0.f;
    h_out[idx] = 0.f;                       // h0 row
    const size_t base = (size_t)idx;

    float cA[8], cB[8], cC[8];
#pragma unroll
    for (int j = 0; j < 8; ++j) cA[j] = po[base + (size_t)j * BD];
#pragma unroll
    for (int j = 0; j < 8; ++j) cB[j] = po[base + (size_t)(8 + j) * BD];
#pragma unroll
    for (int j = 0; j < 8; ++j) cC[j] = po[base + (size_t)(16 + j) * BD];

    size_t off = base;
    for (int g = 0; g < T_DIM / 8; ++g) {
        float cN[8];
        if (g + 3 < T_DIM / 8) {
            const size_t loff = base + (size_t)(g + 3) * 8 * BD;
#pragma unroll
            for (int j = 0; j < 8; ++j) cN[j] = po[loff + (size_t)j * BD];
        }
#pragma unroll
        for (int j = 0; j < 8; ++j) {
            const float p     = cA[j];
            const float ep    = __expf(-p);
            const float alpha = __builtin_amdgcn_rcpf(1.f + ep);    // sigmoid(p)
            const float beta  = ep * alpha;                          // 1-sigmoid(p)
            const float ep2   = ep * ep;
            const float th    = (1.f - ep2) * __builtin_amdgcn_rcpf(1.f + ep2); // tanh(p)
            h = fmaf(alpha, h, beta * th);
            const float sh = __builtin_amdgcn_rcpf(1.f + __expf(-h));
            po[off]         = h * h * sh;   // h * silu(h)
            h_out[off + BD] = h;
            off += BD;
        }
#pragma unroll
        for (int j = 0; j < 8; ++j) { cA[j] = cB[j]; cB[j] = cC[j]; cC[j] = cN[j]; }
    }
}

extern "C" void kernel_launch(void* const* d_in, const int* in_sizes, int n_in,
                              void* d_out, int out_size, void* d_ws, size_t ws_size,
                              hipStream_t stream) {
    const float* x = (const float*)d_in[0];
    const float* W = (const float*)d_in[1];
    const float* b = (const float*)d_in[2];
    float* out = (float*)d_out;                                // outputs / proj (128 MB)
    float* h   = out + (size_t)T_DIM * B_DIM * D_DIM;          // h region (134.2 MB)

    // Scratch in the h region (dead before scan writes h):
    ushort* Xf = (ushort*)h;                                   // 64 MB
    ushort* Wh = Xf + (size_t)M_DIM * K_DIM;                   // 2 MB
    ushort* Wl = Wh + (size_t)N_DIM * K_DIM;                   // 2 MB

    convert_x<<<2048, 256, 0, stream>>>(x, Xf);
    convert_w<<<128, 256, 0, stream>>>(W, Wh, Wl);
    gemm_proj_f16<<<1024, 512, 0, stream>>>(Xf, Wh, Wl, b, out);
    scan_fused<<<BD / 64, 64, 0, stream>>>(out, h);
}

// Round 5
// 279.589 us; speedup vs baseline: 3.6655x; 1.2017x over previous
//
#include <hip/hip_runtime.h>

// T=2048, B=16, D=1024
#define T_DIM 2048
#define B_DIM 16
#define D_DIM 1024
#define M_DIM (T_DIM * B_DIM)   // 32768
#define K_DIM D_DIM
#define N_DIM D_DIM
#define BD    (B_DIM * D_DIM)   // 16384 scan channels
#define NCH   32                // scan chunks
#define CHL   (T_DIM / NCH)     // 64 steps per chunk
#define NQ    (BD / 4)          // 4096 float4 channel-groups

typedef _Float16 f16;
typedef __attribute__((ext_vector_type(8)))  _Float16 f16x8;
typedef __attribute__((ext_vector_type(16))) float    f32x16;

#define GLD16(g, l) __builtin_amdgcn_global_load_lds(                        \
    (const __attribute__((address_space(1))) unsigned*)(g),                  \
    (__attribute__((address_space(3))) unsigned*)(l), 16, 0, 0)

#define CFENCE asm volatile("" ::: "memory")
#define BARRIER do { CFENCE; __builtin_amdgcn_s_barrier(); CFENCE; } while (0)

// ---------- scan step helpers (identical math in all scan kernels) ----------
__device__ __forceinline__ void stepAB(float p, float& A, float& B) {
    const float ep  = __expf(-p);
    const float al  = __builtin_amdgcn_rcpf(1.f + ep);    // sigmoid(p)
    const float be  = ep * al;                             // 1-sigmoid(p)
    const float ep2 = ep * ep;
    const float th  = (1.f - ep2) * __builtin_amdgcn_rcpf(1.f + ep2); // tanh(p)
    A = A * al;
    B = fmaf(al, B, be * th);
}
__device__ __forceinline__ void stepH(float p, float& h) {
    const float ep  = __expf(-p);
    const float al  = __builtin_amdgcn_rcpf(1.f + ep);
    const float be  = ep * al;
    const float ep2 = ep * ep;
    const float th  = (1.f - ep2) * __builtin_amdgcn_rcpf(1.f + ep2);
    h = fmaf(al, h, be * th);
}
__device__ __forceinline__ float outOf(float h) {
    const float sh = __builtin_amdgcn_rcpf(1.f + __expf(-h));
    return h * h * sh;
}

// Tiled fp16 layouts (k-plane c = k>>3, 8 k per plane):
//  A tile (per br 0..127, kt 0..15): [c 8][row 256][8]  = 16384 ushort = 32 KiB
//  B tile (per bc 0..7,   kt 0..15): [c 8][col 128][8]  =  8192 ushort = 16 KiB

// ---------- pre-pass 1: x fp32 -> Xf fp16 (A-tiled) ----------
__global__ __launch_bounds__(256) void convert_x(const float* __restrict__ x,
                                                 ushort* __restrict__ Xf) {
    __shared__ ushort tile[16384];
    const int b   = (int)blockIdx.x;     // 2048 = 128 br x 16 kt
    const int br  = b >> 4;
    const int kt  = b & 15;
    const int tid = (int)threadIdx.x;
#pragma unroll
    for (int i = 0; i < 16; ++i) {
        const int fi  = tid + i * 256;   // 0..4095
        const int row = fi >> 4;         // 0..255
        const int kq  = fi & 15;         // float4 index in 64-k row
        const float4 v = *(const float4*)&x[(size_t)(br * 256 + row) * K_DIM + kt * 64 + kq * 4];
        ushort4 u;
        u.x = __builtin_bit_cast(unsigned short, (f16)v.x);
        u.y = __builtin_bit_cast(unsigned short, (f16)v.y);
        u.z = __builtin_bit_cast(unsigned short, (f16)v.z);
        u.w = __builtin_bit_cast(unsigned short, (f16)v.w);
        const int idx = ((kq >> 1) * 256 + row) * 8 + (kq & 1) * 4;
        *(ushort4*)&tile[idx] = u;
    }
    __syncthreads();
    const uint4* s = (const uint4*)tile;                 // 2048 x 16B
    uint4* d = (uint4*)(Xf + (size_t)b * 16384);
#pragma unroll
    for (int i = 0; i < 8; ++i) d[tid + i * 256] = s[tid + i * 256];
}

// ---------- pre-pass 2: W fp32 -> Wh + Wl*2048 fp16 (B-tiled) ----------
__global__ __launch_bounds__(256) void convert_w(const float* __restrict__ W,
                                                 ushort* __restrict__ Wh,
                                                 ushort* __restrict__ Wl) {
    __shared__ ushort th[8192];
    __shared__ ushort tl[8192];
    const int b   = (int)blockIdx.x;     // 128 = 8 bc x 16 kt
    const int bc  = b >> 4;
    const int kt  = b & 15;
    const int tid = (int)threadIdx.x;
#pragma unroll
    for (int i = 0; i < 8; ++i) {
        const int fi  = tid + i * 256;   // 0..2047
        const int col = fi >> 4;         // 0..127
        const int kq  = fi & 15;
        const float4 v = *(const float4*)&W[(size_t)(bc * 128 + col) * K_DIM + kt * 64 + kq * 4];
        const float f[4] = {v.x, v.y, v.z, v.w};
        ushort4 uh, ul;
        unsigned short* ph = (unsigned short*)&uh;
        unsigned short* pl = (unsigned short*)&ul;
#pragma unroll
        for (int j = 0; j < 4; ++j) {
            const f16 hh = (f16)f[j];
            const float r = f[j] - (float)hh;
            const f16 hl = (f16)(r * 2048.f);
            ph[j] = __builtin_bit_cast(unsigned short, hh);
            pl[j] = __builtin_bit_cast(unsigned short, hl);
        }
        const int idx = ((kq >> 1) * 128 + col) * 8 + (kq & 1) * 4;
        *(ushort4*)&th[idx] = uh;
        *(ushort4*)&tl[idx] = ul;
    }
    __syncthreads();
    const uint4* sh = (const uint4*)th;                  // 1024 x 16B
    const uint4* sl = (const uint4*)tl;
    uint4* dh = (uint4*)(Wh + (size_t)b * 8192);
    uint4* dl = (uint4*)(Wl + (size_t)b * 8192);
#pragma unroll
    for (int i = 0; i < 4; ++i) {
        dh[tid + i * 256] = sh[tid + i * 256];
        dl[tid + i * 256] = sl[tid + i * 256];
    }
}

// ---------- GEMM: proj = Xf*(Wh + Wl/2048)^T + b ----------
// 256x128(real)x dual tile, BK=64, 8 waves, double-buffered LDS, counted vmcnt.
__global__ __launch_bounds__(512, 2) void gemm_proj_f16(const ushort* __restrict__ Xf,
                                                        const ushort* __restrict__ Wh,
                                                        const ushort* __restrict__ Wl,
                                                        const float* __restrict__ bias,
                                                        float* __restrict__ proj) {
    __shared__ ushort sA[2][16384];   // 2 x 32 KiB
    __shared__ ushort sBh[2][8192];   // 2 x 16 KiB
    __shared__ ushort sBl[2][8192];   // 2 x 16 KiB

    const int bid = (int)blockIdx.x;                 // 1024 blocks
    const int swz = (bid & 7) * 128 + (bid >> 3);    // XCD x owns br-slab [x*16, x*16+16)
    const int bc  = swz & 7;
    const int br  = swz >> 3;
    const int tid  = (int)threadIdx.x;
    const int lane = tid & 63;
    const int wid  = tid >> 6;
    const int wr = wid >> 2;         // 0..1 : 128-row half
    const int wc = wid & 3;          // 0..3 : 32-col slice
    const int kh  = lane >> 5;
    const int r32 = lane & 31;

    const char* aG  = (const char*)(Xf + (size_t)br * 16 * 16384);
    const char* bhG = (const char*)(Wh + (size_t)bc * 16 * 8192);
    const char* blG = (const char*)(Wl + (size_t)bc * 16 * 8192);

    f32x16 aH[4], aL[4];
#pragma unroll
    for (int m = 0; m < 4; ++m)
#pragma unroll
        for (int r = 0; r < 16; ++r) { aH[m][r] = 0.f; aL[m][r] = 0.f; }

#define STAGE(t, buf) do {                                                      \
        const size_t ta = (size_t)(t) * 32768;                                  \
        const size_t tb = (size_t)(t) * 16384;                                  \
        GLD16(aG  + ta + tid * 16,         (char*)&sA[buf][0]  + tid * 16);     \
        GLD16(aG  + ta + tid * 16 + 8192,  (char*)&sA[buf][0]  + tid * 16 + 8192);  \
        GLD16(aG  + ta + tid * 16 + 16384, (char*)&sA[buf][0]  + tid * 16 + 16384); \
        GLD16(aG  + ta + tid * 16 + 24576, (char*)&sA[buf][0]  + tid * 16 + 24576); \
        GLD16(bhG + tb + tid * 16,         (char*)&sBh[buf][0] + tid * 16);     \
        GLD16(bhG + tb + tid * 16 + 8192,  (char*)&sBh[buf][0] + tid * 16 + 8192);  \
        GLD16(blG + tb + tid * 16,         (char*)&sBl[buf][0] + tid * 16);     \
        GLD16(blG + tb + tid * 16 + 8192,  (char*)&sBl[buf][0] + tid * 16 + 8192);  \
    } while (0)

    STAGE(0, 0);
    STAGE(1, 1);

    for (int t = 0; t < 16; ++t) {
        if (t < 15) asm volatile("s_waitcnt vmcnt(8)" ::: "memory");
        else        asm volatile("s_waitcnt vmcnt(0)" ::: "memory");
        BARRIER;
        const int cur = t & 1;
#pragma unroll
        for (int kk = 0; kk < 4; ++kk) {
            const int c0 = kk * 2 + kh;
            const int ab = (c0 * 256 + wr * 128 + r32) * 8;
            const int bb = (c0 * 128 + wc * 32 + r32) * 8;
            f16x8 fa0 = *(const f16x8*)&sA[cur][ab];
            f16x8 fa1 = *(const f16x8*)&sA[cur][ab + 32 * 8];
            f16x8 fa2 = *(const f16x8*)&sA[cur][ab + 64 * 8];
            f16x8 fa3 = *(const f16x8*)&sA[cur][ab + 96 * 8];
            f16x8 fh  = *(const f16x8*)&sBh[cur][bb];
            f16x8 fl  = *(const f16x8*)&sBl[cur][bb];
            aH[0] = __builtin_amdgcn_mfma_f32_32x32x16_f16(fa0, fh, aH[0], 0, 0, 0);
            aL[0] = __builtin_amdgcn_mfma_f32_32x32x16_f16(fa0, fl, aL[0], 0, 0, 0);
            aH[1] = __builtin_amdgcn_mfma_f32_32x32x16_f16(fa1, fh, aH[1], 0, 0, 0);
            aL[1] = __builtin_amdgcn_mfma_f32_32x32x16_f16(fa1, fl, aL[1], 0, 0, 0);
            aH[2] = __builtin_amdgcn_mfma_f32_32x32x16_f16(fa2, fh, aH[2], 0, 0, 0);
            aL[2] = __builtin_amdgcn_mfma_f32_32x32x16_f16(fa2, fl, aL[2], 0, 0, 0);
            aH[3] = __builtin_amdgcn_mfma_f32_32x32x16_f16(fa3, fh, aH[3], 0, 0, 0);
            aL[3] = __builtin_amdgcn_mfma_f32_32x32x16_f16(fa3, fl, aL[3], 0, 0, 0);
        }
        BARRIER;
        if (t < 14) STAGE(t + 2, cur);
    }
#undef STAGE

    // Epilogue: combine H + L/2048 + bias in registers.
    // C/D layout: col = lane&31, row = (r&3) + 8*(r>>2) + 4*(lane>>5)  (verified r2/r3)
    const int colg = bc * 128 + wc * 32 + r32;
    const float bz = bias[colg];
#pragma unroll
    for (int m = 0; m < 4; ++m) {
        const int rb = br * 256 + wr * 128 + m * 32 + 4 * kh;
#pragma unroll
        for (int r = 0; r < 16; ++r) {
            const int row = rb + (r & 3) + 8 * (r >> 2);
            proj[(size_t)row * N_DIM + colg] = aH[m][r] + aL[m][r] * (1.f / 2048.f) + bz;
        }
    }
}

// ---------- Scan pass 1: per-chunk affine composition (A,B) ----------
// Thread (c, q) scans t in [c*CHL, (c+1)*CHL) for channels 4q..4q+3.
__global__ __launch_bounds__(256) void scan_pass1(const float* __restrict__ po,
                                                  float4* __restrict__ Ac,
                                                  float4* __restrict__ Bc) {
    const int blk = (int)blockIdx.x;         // 496 = 31 chunks x 16 (chunk 31 unused)
    const int c   = blk >> 4;
    const int q   = (blk & 15) * 256 + (int)threadIdx.x;   // 0..4095
    const float* pp = po + (size_t)c * CHL * BD + (size_t)q * 4;

    float4 A = make_float4(1.f, 1.f, 1.f, 1.f);
    float4 B = make_float4(0.f, 0.f, 0.f, 0.f);
    float4 cur[4], nxt[4];
#pragma unroll
    for (int j = 0; j < 4; ++j) cur[j] = *(const float4*)&pp[(size_t)j * BD];
    for (int g = 0; g < CHL / 4; ++g) {
        if (g + 1 < CHL / 4) {
#pragma unroll
            for (int j = 0; j < 4; ++j)
                nxt[j] = *(const float4*)&pp[(size_t)((g + 1) * 4 + j) * BD];
        }
#pragma unroll
        for (int j = 0; j < 4; ++j) {
            stepAB(cur[j].x, A.x, B.x);
            stepAB(cur[j].y, A.y, B.y);
            stepAB(cur[j].z, A.z, B.z);
            stepAB(cur[j].w, A.w, B.w);
        }
#pragma unroll
        for (int j = 0; j < 4; ++j) cur[j] = nxt[j];
    }
    Ac[c * NQ + q] = A;
    Bc[c * NQ + q] = B;
}

// ---------- Scan pass 2: prefix-compose + rescan, write out (in place) + h ----------
__global__ __launch_bounds__(256) void scan_pass2(float* __restrict__ po,
                                                  const float4* __restrict__ Ac,
                                                  const float4* __restrict__ Bc,
                                                  float* __restrict__ h_out) {
    const int blk = (int)blockIdx.x;         // 512 = 32 chunks x 16
    const int c   = blk >> 4;
    const int q   = (blk & 15) * 256 + (int)threadIdx.x;

    float4 h = make_float4(0.f, 0.f, 0.f, 0.f);
    for (int j = 0; j < c; ++j) {
        const float4 A = Ac[j * NQ + q];
        const float4 B = Bc[j * NQ + q];
        h.x = fmaf(A.x, h.x, B.x);
        h.y = fmaf(A.y, h.y, B.y);
        h.z = fmaf(A.z, h.z, B.z);
        h.w = fmaf(A.w, h.w, B.w);
    }
    if (c == 0) *(float4*)&h_out[(size_t)q * 4] = make_float4(0.f, 0.f, 0.f, 0.f);

    float* pp = po + (size_t)c * CHL * BD + (size_t)q * 4;
    float* hp = h_out + (size_t)c * CHL * BD + (size_t)q * 4 + BD;   // h[t+1] rows

    float4 cur[4], nxt[4];
#pragma unroll
    for (int j = 0; j < 4; ++j) cur[j] = *(const float4*)&pp[(size_t)j * BD];
    for (int g = 0; g < CHL / 4; ++g) {
        if (g + 1 < CHL / 4) {
#pragma unroll
            for (int j = 0; j < 4; ++j)
                nxt[j] = *(const float4*)&pp[(size_t)((g + 1) * 4 + j) * BD];
        }
#pragma unroll
        for (int j = 0; j < 4; ++j) {
            const size_t so = (size_t)(g * 4 + j) * BD;
            stepH(cur[j].x, h.x);
            stepH(cur[j].y, h.y);
            stepH(cur[j].z, h.z);
            stepH(cur[j].w, h.w);
            float4 o;
            o.x = outOf(h.x); o.y = outOf(h.y); o.z = outOf(h.z); o.w = outOf(h.w);
            *(float4*)&pp[so] = o;    // out_t overwrites proj_t (same thread)
            *(float4*)&hp[so] = h;    // h_{t+1}
        }
#pragma unroll
        for (int j = 0; j < 4; ++j) cur[j] = nxt[j];
    }
}

// ---------- fallback sequential scan (used only if ws_size < 4 MB) ----------
__global__ __launch_bounds__(64) void scan_fused(float* __restrict__ po,
                                                 float* __restrict__ h_out) {
    const int idx = (int)blockIdx.x * 64 + (int)threadIdx.x;
    float h = 0.f;
    h_out[idx] = 0.f;
    size_t off = (size_t)idx;
#pragma unroll 4
    for (int t = 0; t < T_DIM; ++t) {
        float p = po[off];
        stepH(p, h);
        po[off] = outOf(h);
        h_out[off + BD] = h;
        off += BD;
    }
}

extern "C" void kernel_launch(void* const* d_in, const int* in_sizes, int n_in,
                              void* d_out, int out_size, void* d_ws, size_t ws_size,
                              hipStream_t stream) {
    const float* x = (const float*)d_in[0];
    const float* W = (const float*)d_in[1];
    const float* b = (const float*)d_in[2];
    float* out = (float*)d_out;                                // outputs / proj (128 MB)
    float* h   = out + (size_t)T_DIM * B_DIM * D_DIM;          // h region (134.2 MB)

    // Scratch in the h region (dead before scan writes h):
    ushort* Xf = (ushort*)h;                                   // 64 MB
    ushort* Wh = Xf + (size_t)M_DIM * K_DIM;                   // 2 MB
    ushort* Wl = Wh + (size_t)N_DIM * K_DIM;                   // 2 MB

    convert_x<<<2048, 256, 0, stream>>>(x, Xf);
    convert_w<<<128, 256, 0, stream>>>(W, Wh, Wl);
    gemm_proj_f16<<<1024, 512, 0, stream>>>(Xf, Wh, Wl, b, out);

    if (ws_size >= (size_t)4 * 1024 * 1024) {
        float4* Ac = (float4*)d_ws;                  // [NCH][NQ] = 2 MB
        float4* Bc = Ac + (size_t)NCH * NQ;          // 2 MB
        scan_pass1<<<(NCH - 1) * 16, 256, 0, stream>>>(out, Ac, Bc);
        scan_pass2<<<NCH * 16, 256, 0, stream>>>(out, Ac, Bc, h);
    } else {
        scan_fused<<<BD / 64, 64, 0, stream>>>(out, h);
    }
}

// Round 6
// 226.805 us; speedup vs baseline: 4.5186x; 1.2327x over previous
//
#include <hip/hip_runtime.h>

// T=2048, B=16, D=1024
#define T_DIM 2048
#define B_DIM 16
#define D_DIM 1024
#define M_DIM (T_DIM * B_DIM)   // 32768
#define K_DIM D_DIM
#define N_DIM D_DIM
#define BD    (B_DIM * D_DIM)   // 16384 scan channels
#define NCH   32                // scan chunks
#define CHL   (T_DIM / NCH)     // 64 steps per chunk
#define NQ    (BD / 4)          // 4096 float4 channel-groups

typedef _Float16 f16;
typedef __attribute__((ext_vector_type(8)))  _Float16 f16x8;
typedef __attribute__((ext_vector_type(4)))  float    f32x4;

#define GLD16(g, l) __builtin_amdgcn_global_load_lds(                        \
    (const __attribute__((address_space(1))) unsigned*)(g),                  \
    (__attribute__((address_space(3))) unsigned*)(l), 16, 0, 0)

#define CFENCE asm volatile("" ::: "memory")
#define BARRIER do { CFENCE; __builtin_amdgcn_s_barrier(); CFENCE; } while (0)

// ---------- scan step helpers ----------
__device__ __forceinline__ void stepAB(float p, float& A, float& B) {
    const float ep  = __expf(-p);
    const float al  = __builtin_amdgcn_rcpf(1.f + ep);    // sigmoid(p)
    const float be  = ep * al;                             // 1-sigmoid(p)
    const float ep2 = ep * ep;
    const float th  = (1.f - ep2) * __builtin_amdgcn_rcpf(1.f + ep2); // tanh(p)
    A = A * al;
    B = fmaf(al, B, be * th);
}
__device__ __forceinline__ void stepH(float p, float& h) {
    const float ep  = __expf(-p);
    const float al  = __builtin_amdgcn_rcpf(1.f + ep);
    const float be  = ep * al;
    const float ep2 = ep * ep;
    const float th  = (1.f - ep2) * __builtin_amdgcn_rcpf(1.f + ep2);
    h = fmaf(al, h, be * th);
}
__device__ __forceinline__ float outOf(float h) {
    const float sh = __builtin_amdgcn_rcpf(1.f + __expf(-h));
    return h * h * sh;
}

// Tile format (both A and B): per (slab, kt) tile of 128 rows x 64 k:
//   ushort idx = ((c*128) + row)*8 + j  where c = k>>3 (0..7), j = k&7
//   tile = 8192 ushort = 16 KiB; tiles consecutive: base = (slab*16 + kt)*8192.
// A 16x16x32 fragment read: lane reads 8 f16 at (row = base+(lane&15),
//   c = kc*4 + (lane>>4)) -> 16 consecutive rows x 16B = 256B contiguous: conflict-free.

// ---------- pre-pass 1: x fp32 -> Xf f16 (tiled, 128-row slabs) ----------
__global__ __launch_bounds__(256) void convert_x(const float* __restrict__ x,
                                                 ushort* __restrict__ Xf) {
    __shared__ ushort tile[8192];
    const int b   = (int)blockIdx.x;     // 4096 = 256 br x 16 kt
    const int br  = b >> 4;
    const int kt  = b & 15;
    const int tid = (int)threadIdx.x;
#pragma unroll
    for (int i = 0; i < 8; ++i) {
        const int fi  = tid + i * 256;   // 0..2047 float4s
        const int row = fi >> 4;         // 0..127
        const int kq  = fi & 15;         // float4 index within 64-k row
        const float4 v = *(const float4*)&x[(size_t)(br * 128 + row) * K_DIM + kt * 64 + kq * 4];
        ushort4 u;
        u.x = __builtin_bit_cast(unsigned short, (f16)v.x);
        u.y = __builtin_bit_cast(unsigned short, (f16)v.y);
        u.z = __builtin_bit_cast(unsigned short, (f16)v.z);
        u.w = __builtin_bit_cast(unsigned short, (f16)v.w);
        const int idx = ((kq >> 1) * 128 + row) * 8 + (kq & 1) * 4;
        *(ushort4*)&tile[idx] = u;
    }
    __syncthreads();
    const uint4* s = (const uint4*)tile;                 // 1024 x 16B
    uint4* d = (uint4*)(Xf + (size_t)b * 8192);
#pragma unroll
    for (int i = 0; i < 4; ++i) d[tid + i * 256] = s[tid + i * 256];
}

// ---------- pre-pass 2: W fp32 -> Wh f16 (tiled, 128-col slabs) ----------
__global__ __launch_bounds__(256) void convert_w(const float* __restrict__ W,
                                                 ushort* __restrict__ Wh) {
    __shared__ ushort th[8192];
    const int b   = (int)blockIdx.x;     // 128 = 8 bc x 16 kt
    const int bc  = b >> 4;
    const int kt  = b & 15;
    const int tid = (int)threadIdx.x;
#pragma unroll
    for (int i = 0; i < 8; ++i) {
        const int fi  = tid + i * 256;
        const int col = fi >> 4;
        const int kq  = fi & 15;
        const float4 v = *(const float4*)&W[(size_t)(bc * 128 + col) * K_DIM + kt * 64 + kq * 4];
        ushort4 u;
        u.x = __builtin_bit_cast(unsigned short, (f16)v.x);
        u.y = __builtin_bit_cast(unsigned short, (f16)v.y);
        u.z = __builtin_bit_cast(unsigned short, (f16)v.z);
        u.w = __builtin_bit_cast(unsigned short, (f16)v.w);
        const int idx = ((kq >> 1) * 128 + col) * 8 + (kq & 1) * 4;
        *(ushort4*)&th[idx] = u;
    }
    __syncthreads();
    const uint4* s = (const uint4*)th;
    uint4* d = (uint4*)(Wh + (size_t)b * 8192);
#pragma unroll
    for (int i = 0; i < 4; ++i) d[tid + i * 256] = s[tid + i * 256];
}

// ---------- GEMM: proj = Xf * Wh^T + b  (single-term f16, 16x16x32 MFMA) ----------
// 128x128 block, BK=64, 4 waves (2x2), wave-tile 64x64 = 4x4 frags.
// Double-buffered LDS (64 KiB -> 2 blocks/CU), counted vmcnt prefetch.
__global__ __launch_bounds__(256, 2) void gemm_proj_f16(const ushort* __restrict__ Xf,
                                                        const ushort* __restrict__ Wh,
                                                        const float* __restrict__ bias,
                                                        float* __restrict__ proj) {
    __shared__ ushort sA[2][8192];   // 2 x 16 KiB
    __shared__ ushort sB[2][8192];   // 2 x 16 KiB

    const int bid = (int)blockIdx.x;                 // 2048 blocks
    const int swz = (bid & 7) * 256 + (bid >> 3);    // XCD x owns br in [x*32, x*32+32)
    const int bc  = swz & 7;                         // 0..7
    const int br  = swz >> 3;                        // 0..255
    const int tid  = (int)threadIdx.x;
    const int lane = tid & 63;
    const int wid  = tid >> 6;
    const int wr = (wid >> 1) * 64;  // 0 / 64
    const int wc = (wid & 1) * 64;   // 0 / 64
    const int l16 = lane & 15;
    const int lc  = lane >> 4;       // 0..3: k-chunk within K32

    const char* aG = (const char*)(Xf + (size_t)br * 16 * 8192);
    const char* bG = (const char*)(Wh + (size_t)bc * 16 * 8192);

    f32x4 acc[4][4];
#pragma unroll
    for (int m = 0; m < 4; ++m)
#pragma unroll
        for (int n = 0; n < 4; ++n)
#pragma unroll
            for (int r = 0; r < 4; ++r) acc[m][n][r] = 0.f;

#define STAGE(t, buf) do {                                                   \
        const size_t tb = (size_t)(t) * 16384;                               \
        GLD16(aG + tb + tid * 16,         (char*)&sA[buf][0] + tid * 16);    \
        GLD16(aG + tb + tid * 16 + 4096,  (char*)&sA[buf][0] + tid * 16 + 4096);  \
        GLD16(aG + tb + tid * 16 + 8192,  (char*)&sA[buf][0] + tid * 16 + 8192);  \
        GLD16(aG + tb + tid * 16 + 12288, (char*)&sA[buf][0] + tid * 16 + 12288); \
        GLD16(bG + tb + tid * 16,         (char*)&sB[buf][0] + tid * 16);    \
        GLD16(bG + tb + tid * 16 + 4096,  (char*)&sB[buf][0] + tid * 16 + 4096);  \
        GLD16(bG + tb + tid * 16 + 8192,  (char*)&sB[buf][0] + tid * 16 + 8192);  \
        GLD16(bG + tb + tid * 16 + 12288, (char*)&sB[buf][0] + tid * 16 + 12288); \
    } while (0)

    STAGE(0, 0);
    STAGE(1, 1);

    for (int t = 0; t < 16; ++t) {
        if (t < 15) asm volatile("s_waitcnt vmcnt(8)" ::: "memory");
        else        asm volatile("s_waitcnt vmcnt(0)" ::: "memory");
        BARRIER;
        const int cur = t & 1;
#pragma unroll
        for (int kc = 0; kc < 2; ++kc) {
            const int cbase = (kc * 4 + lc) * 128;
            f16x8 fa[4], fb[4];
#pragma unroll
            for (int m = 0; m < 4; ++m)
                fa[m] = *(const f16x8*)&sA[cur][(cbase + wr + m * 16 + l16) * 8];
#pragma unroll
            for (int n = 0; n < 4; ++n)
                fb[n] = *(const f16x8*)&sB[cur][(cbase + wc + n * 16 + l16) * 8];
#pragma unroll
            for (int m = 0; m < 4; ++m)
#pragma unroll
                for (int n = 0; n < 4; ++n)
                    acc[m][n] = __builtin_amdgcn_mfma_f32_16x16x32_f16(fa[m], fb[n], acc[m][n], 0, 0, 0);
        }
        BARRIER;
        if (t < 14) STAGE(t + 2, cur);
    }
#undef STAGE

    // C/D layout (16x16): col = lane&15, row = (lane>>4)*4 + r
#pragma unroll
    for (int n = 0; n < 4; ++n) {
        const int colg = bc * 128 + wc + n * 16 + l16;
        const float bz = bias[colg];
#pragma unroll
        for (int m = 0; m < 4; ++m) {
            const int rowg = br * 128 + wr + m * 16 + lc * 4;
#pragma unroll
            for (int r = 0; r < 4; ++r)
                proj[(size_t)(rowg + r) * N_DIM + colg] = acc[m][n][r] + bz;
        }
    }
}

// ---------- Scan pass 1: per-chunk affine composition (A,B) ----------
__global__ __launch_bounds__(256) void scan_pass1(const float* __restrict__ po,
                                                  float4* __restrict__ Ac,
                                                  float4* __restrict__ Bc) {
    const int blk = (int)blockIdx.x;         // 496 = 31 chunks x 16
    const int c   = blk >> 4;
    const int q   = (blk & 15) * 256 + (int)threadIdx.x;   // 0..4095
    const float* pp = po + (size_t)c * CHL * BD + (size_t)q * 4;

    float4 A = make_float4(1.f, 1.f, 1.f, 1.f);
    float4 B = make_float4(0.f, 0.f, 0.f, 0.f);
    float4 cur[4], nxt[4];
#pragma unroll
    for (int j = 0; j < 4; ++j) cur[j] = *(const float4*)&pp[(size_t)j * BD];
    for (int g = 0; g < CHL / 4; ++g) {
        if (g + 1 < CHL / 4) {
#pragma unroll
            for (int j = 0; j < 4; ++j)
                nxt[j] = *(const float4*)&pp[(size_t)((g + 1) * 4 + j) * BD];
        }
#pragma unroll
        for (int j = 0; j < 4; ++j) {
            stepAB(cur[j].x, A.x, B.x);
            stepAB(cur[j].y, A.y, B.y);
            stepAB(cur[j].z, A.z, B.z);
            stepAB(cur[j].w, A.w, B.w);
        }
#pragma unroll
        for (int j = 0; j < 4; ++j) cur[j] = nxt[j];
    }
    Ac[c * NQ + q] = A;
    Bc[c * NQ + q] = B;
}

// ---------- Scan pass 2: prefix-compose + rescan, write out (in place) + h ----------
__global__ __launch_bounds__(256) void scan_pass2(float* __restrict__ po,
                                                  const float4* __restrict__ Ac,
                                                  const float4* __restrict__ Bc,
                                                  float* __restrict__ h_out) {
    const int blk = (int)blockIdx.x;         // 512 = 32 chunks x 16
    const int c   = blk >> 4;
    const int q   = (blk & 15) * 256 + (int)threadIdx.x;

    float4 h = make_float4(0.f, 0.f, 0.f, 0.f);
    for (int j = 0; j < c; ++j) {
        const float4 A = Ac[j * NQ + q];
        const float4 B = Bc[j * NQ + q];
        h.x = fmaf(A.x, h.x, B.x);
        h.y = fmaf(A.y, h.y, B.y);
        h.z = fmaf(A.z, h.z, B.z);
        h.w = fmaf(A.w, h.w, B.w);
    }
    if (c == 0) *(float4*)&h_out[(size_t)q * 4] = make_float4(0.f, 0.f, 0.f, 0.f);

    float* pp = po + (size_t)c * CHL * BD + (size_t)q * 4;
    float* hp = h_out + (size_t)c * CHL * BD + (size_t)q * 4 + BD;   // h[t+1]

    float4 cur[4], nxt[4];
#pragma unroll
    for (int j = 0; j < 4; ++j) cur[j] = *(const float4*)&pp[(size_t)j * BD];
    for (int g = 0; g < CHL / 4; ++g) {
        if (g + 1 < CHL / 4) {
#pragma unroll
            for (int j = 0; j < 4; ++j)
                nxt[j] = *(const float4*)&pp[(size_t)((g + 1) * 4 + j) * BD];
        }
#pragma unroll
        for (int j = 0; j < 4; ++j) {
            const size_t so = (size_t)(g * 4 + j) * BD;
            stepH(cur[j].x, h.x);
            stepH(cur[j].y, h.y);
            stepH(cur[j].z, h.z);
            stepH(cur[j].w, h.w);
            float4 o;
            o.x = outOf(h.x); o.y = outOf(h.y); o.z = outOf(h.z); o.w = outOf(h.w);
            *(float4*)&pp[so] = o;    // out_t overwrites proj_t
            *(float4*)&hp[so] = h;    // h_{t+1}
        }
#pragma unroll
        for (int j = 0; j < 4; ++j) cur[j] = nxt[j];
    }
}

// ---------- fallback sequential scan (if ws_size < 4 MB) ----------
__global__ __launch_bounds__(64) void scan_fused(float* __restrict__ po,
                                                 float* __restrict__ h_out) {
    const int idx = (int)blockIdx.x * 64 + (int)threadIdx.x;
    float h = 0.f;
    h_out[idx] = 0.f;
    size_t off = (size_t)idx;
#pragma unroll 4
    for (int t = 0; t < T_DIM; ++t) {
        float p = po[off];
        stepH(p, h);
        po[off] = outOf(h);
        h_out[off + BD] = h;
        off += BD;
    }
}

extern "C" void kernel_launch(void* const* d_in, const int* in_sizes, int n_in,
                              void* d_out, int out_size, void* d_ws, size_t ws_size,
                              hipStream_t stream) {
    const float* x = (const float*)d_in[0];
    const float* W = (const float*)d_in[1];
    const float* b = (const float*)d_in[2];
    float* out = (float*)d_out;                                // outputs / proj (128 MB)
    float* h   = out + (size_t)T_DIM * B_DIM * D_DIM;          // h region (134.2 MB)

    // Scratch in the h region (dead before scan writes h):
    ushort* Xf = (ushort*)h;                                   // 64 MB
    ushort* Wh = Xf + (size_t)M_DIM * K_DIM;                   // 2 MB

    convert_x<<<4096, 256, 0, stream>>>(x, Xf);
    convert_w<<<128, 256, 0, stream>>>(W, Wh);
    gemm_proj_f16<<<2048, 256, 0, stream>>>(Xf, Wh, b, out);

    if (ws_size >= (size_t)4 * 1024 * 1024) {
        float4* Ac = (float4*)d_ws;                  // [NCH][NQ] = 2 MB
        float4* Bc = Ac + (size_t)NCH * NQ;          // 2 MB
        scan_pass1<<<(NCH - 1) * 16, 256, 0, stream>>>(out, Ac, Bc);
        scan_pass2<<<NCH * 16, 256, 0, stream>>>(out, Ac, Bc, h);
    } else {
        scan_fused<<<BD / 64, 64, 0, stream>>>(out, h);
    }
}

// Round 7
// 213.800 us; speedup vs baseline: 4.7934x; 1.0608x over previous
//
#include <hip/hip_runtime.h>

// T=2048, B=16, D=1024
#define T_DIM 2048
#define B_DIM 16
#define D_DIM 1024
#define M_DIM (T_DIM * B_DIM)   // 32768
#define K_DIM D_DIM
#define N_DIM D_DIM
#define BD    (B_DIM * D_DIM)   // 16384 scan channels
#define NCH   32                // scan chunks
#define CHL   (T_DIM / NCH)     // 64 steps per chunk
#define NQ    (BD / 4)          // 4096 float4 channel-groups (legacy path)

typedef _Float16 f16;
typedef __attribute__((ext_vector_type(8)))  _Float16 f16x8;
typedef __attribute__((ext_vector_type(4)))  float    f32x4;

#define GLD16(g, l) __builtin_amdgcn_global_load_lds(                        \
    (const __attribute__((address_space(1))) unsigned*)(g),                  \
    (__attribute__((address_space(3))) unsigned*)(l), 16, 0, 0)

#define CFENCE asm volatile("" ::: "memory")
#define BARRIER do { CFENCE; __builtin_amdgcn_s_barrier(); CFENCE; } while (0)

// ---------- scan step helpers ----------
__device__ __forceinline__ void stepAB(float p, float& A, float& B) {
    const float ep  = __expf(-p);
    const float al  = __builtin_amdgcn_rcpf(1.f + ep);    // sigmoid(p)
    const float be  = ep * al;                             // 1-sigmoid(p)
    const float ep2 = ep * ep;
    const float th  = (1.f - ep2) * __builtin_amdgcn_rcpf(1.f + ep2); // tanh(p)
    A = A * al;
    B = fmaf(al, B, be * th);
}
__device__ __forceinline__ void stepH(float p, float& h) {
    const float ep  = __expf(-p);
    const float al  = __builtin_amdgcn_rcpf(1.f + ep);
    const float be  = ep * al;
    const float ep2 = ep * ep;
    const float th  = (1.f - ep2) * __builtin_amdgcn_rcpf(1.f + ep2);
    h = fmaf(al, h, be * th);
}
__device__ __forceinline__ float outOf(float h) {
    const float sh = __builtin_amdgcn_rcpf(1.f + __expf(-h));
    return h * h * sh;
}

// Tile format (A and B): per (slab, kt) tile of 128 rows x 64 k:
//   ushort idx = (c*128 + row)*8 + j, c = k>>3, j = k&7; tile = 16 KiB.

// ---------- pre-pass 1: x fp32 -> Xf f16 (tiled, 128-row slabs) ----------
__global__ __launch_bounds__(256) void convert_x(const float* __restrict__ x,
                                                 ushort* __restrict__ Xf) {
    __shared__ ushort tile[8192];
    const int b   = (int)blockIdx.x;     // 4096 = 256 br x 16 kt
    const int br  = b >> 4;
    const int kt  = b & 15;
    const int tid = (int)threadIdx.x;
#pragma unroll
    for (int i = 0; i < 8; ++i) {
        const int fi  = tid + i * 256;   // 0..2047 float4s
        const int row = fi >> 4;         // 0..127
        const int kq  = fi & 15;
        const float4 v = *(const float4*)&x[(size_t)(br * 128 + row) * K_DIM + kt * 64 + kq * 4];
        ushort4 u;
        u.x = __builtin_bit_cast(unsigned short, (f16)v.x);
        u.y = __builtin_bit_cast(unsigned short, (f16)v.y);
        u.z = __builtin_bit_cast(unsigned short, (f16)v.z);
        u.w = __builtin_bit_cast(unsigned short, (f16)v.w);
        const int idx = ((kq >> 1) * 128 + row) * 8 + (kq & 1) * 4;
        *(ushort4*)&tile[idx] = u;
    }
    __syncthreads();
    const uint4* s = (const uint4*)tile;
    uint4* d = (uint4*)(Xf + (size_t)b * 8192);
#pragma unroll
    for (int i = 0; i < 4; ++i) d[tid + i * 256] = s[tid + i * 256];
}

// ---------- pre-pass 2: W fp32 -> Wh f16 (tiled, 128-col slabs) ----------
__global__ __launch_bounds__(256) void convert_w(const float* __restrict__ W,
                                                 ushort* __restrict__ Wh) {
    __shared__ ushort th[8192];
    const int b   = (int)blockIdx.x;     // 128 = 8 bc x 16 kt
    const int bc  = b >> 4;
    const int kt  = b & 15;
    const int tid = (int)threadIdx.x;
#pragma unroll
    for (int i = 0; i < 8; ++i) {
        const int fi  = tid + i * 256;
        const int col = fi >> 4;
        const int kq  = fi & 15;
        const float4 v = *(const float4*)&W[(size_t)(bc * 128 + col) * K_DIM + kt * 64 + kq * 4];
        ushort4 u;
        u.x = __builtin_bit_cast(unsigned short, (f16)v.x);
        u.y = __builtin_bit_cast(unsigned short, (f16)v.y);
        u.z = __builtin_bit_cast(unsigned short, (f16)v.z);
        u.w = __builtin_bit_cast(unsigned short, (f16)v.w);
        const int idx = ((kq >> 1) * 128 + col) * 8 + (kq & 1) * 4;
        *(ushort4*)&th[idx] = u;
    }
    __syncthreads();
    const uint4* s = (const uint4*)th;
    uint4* d = (uint4*)(Wh + (size_t)b * 8192);
#pragma unroll
    for (int i = 0; i < 4; ++i) d[tid + i * 256] = s[tid + i * 256];
}

// ---------- GEMM: proj = Xf * Wh^T + b  (16x16x32 MFMA, templated output) ----------
// 128x128 block, BK=64, 4 waves (2x2), wave-tile 64x64 = 4x4 frags.
// Double-buffered LDS (64 KiB -> 2 blocks/CU), counted vmcnt prefetch.
template <int OUT16>
__global__ __launch_bounds__(256, 2) void gemm_proj(const ushort* __restrict__ Xf,
                                                    const ushort* __restrict__ Wh,
                                                    const float* __restrict__ bias,
                                                    float* __restrict__ proj32,
                                                    ushort* __restrict__ proj16) {
    __shared__ ushort sA[2][8192];
    __shared__ ushort sB[2][8192];

    const int bid = (int)blockIdx.x;                 // 2048 blocks
    const int swz = (bid & 7) * 256 + (bid >> 3);    // XCD x owns br in [x*32, x*32+32)
    const int bc  = swz & 7;
    const int br  = swz >> 3;
    const int tid  = (int)threadIdx.x;
    const int lane = tid & 63;
    const int wid  = tid >> 6;
    const int wr = (wid >> 1) * 64;
    const int wc = (wid & 1) * 64;
    const int l16 = lane & 15;
    const int lc  = lane >> 4;

    const char* aG = (const char*)(Xf + (size_t)br * 16 * 8192);
    const char* bG = (const char*)(Wh + (size_t)bc * 16 * 8192);

    f32x4 acc[4][4];
#pragma unroll
    for (int m = 0; m < 4; ++m)
#pragma unroll
        for (int n = 0; n < 4; ++n)
#pragma unroll
            for (int r = 0; r < 4; ++r) acc[m][n][r] = 0.f;

#define STAGE(t, buf) do {                                                   \
        const size_t tb = (size_t)(t) * 16384;                               \
        GLD16(aG + tb + tid * 16,         (char*)&sA[buf][0] + tid * 16);    \
        GLD16(aG + tb + tid * 16 + 4096,  (char*)&sA[buf][0] + tid * 16 + 4096);  \
        GLD16(aG + tb + tid * 16 + 8192,  (char*)&sA[buf][0] + tid * 16 + 8192);  \
        GLD16(aG + tb + tid * 16 + 12288, (char*)&sA[buf][0] + tid * 16 + 12288); \
        GLD16(bG + tb + tid * 16,         (char*)&sB[buf][0] + tid * 16);    \
        GLD16(bG + tb + tid * 16 + 4096,  (char*)&sB[buf][0] + tid * 16 + 4096);  \
        GLD16(bG + tb + tid * 16 + 8192,  (char*)&sB[buf][0] + tid * 16 + 8192);  \
        GLD16(bG + tb + tid * 16 + 12288, (char*)&sB[buf][0] + tid * 16 + 12288); \
    } while (0)

    STAGE(0, 0);
    STAGE(1, 1);

    for (int t = 0; t < 16; ++t) {
        if (t < 15) asm volatile("s_waitcnt vmcnt(8)" ::: "memory");
        else        asm volatile("s_waitcnt vmcnt(0)" ::: "memory");
        BARRIER;
        const int cur = t & 1;
#pragma unroll
        for (int kc = 0; kc < 2; ++kc) {
            const int cbase = (kc * 4 + lc) * 128;
            f16x8 fa[4], fb[4];
#pragma unroll
            for (int m = 0; m < 4; ++m)
                fa[m] = *(const f16x8*)&sA[cur][(cbase + wr + m * 16 + l16) * 8];
#pragma unroll
            for (int n = 0; n < 4; ++n)
                fb[n] = *(const f16x8*)&sB[cur][(cbase + wc + n * 16 + l16) * 8];
#pragma unroll
            for (int m = 0; m < 4; ++m)
#pragma unroll
                for (int n = 0; n < 4; ++n)
                    acc[m][n] = __builtin_amdgcn_mfma_f32_16x16x32_f16(fa[m], fb[n], acc[m][n], 0, 0, 0);
        }
        BARRIER;
        if (t < 14) STAGE(t + 2, cur);
    }
#undef STAGE

    // C/D layout (16x16): col = lane&15, row = (lane>>4)*4 + r   (verified r6)
#pragma unroll
    for (int n = 0; n < 4; ++n) {
        const int colg = bc * 128 + wc + n * 16 + l16;
        const float bz = bias[colg];
#pragma unroll
        for (int m = 0; m < 4; ++m) {
            const int rowg = br * 128 + wr + m * 16 + lc * 4;
#pragma unroll
            for (int r = 0; r < 4; ++r) {
                const float v = acc[m][n][r] + bz;
                if constexpr (OUT16)
                    proj16[(size_t)(rowg + r) * N_DIM + colg] =
                        __builtin_bit_cast(unsigned short, (f16)v);
                else
                    proj32[(size_t)(rowg + r) * N_DIM + colg] = v;
            }
        }
    }
}

// ---------- Scan pass 1 (f16 proj, 8 channels/thread) ----------
__global__ __launch_bounds__(256) void scan_pass1h(const ushort* __restrict__ po,
                                                   float* __restrict__ Ac,
                                                   float* __restrict__ Bc) {
    const int blk = (int)blockIdx.x;         // 248 = 31 chunks x 8
    const int c   = blk >> 3;
    const int q   = (blk & 7) * 256 + (int)threadIdx.x;   // 0..2047
    const ushort* pp = po + (size_t)c * CHL * BD + (size_t)q * 8;

    float A[8], B[8];
#pragma unroll
    for (int e = 0; e < 8; ++e) { A[e] = 1.f; B[e] = 0.f; }

    f16x8 cur[4], nxt[4];
#pragma unroll
    for (int j = 0; j < 4; ++j) cur[j] = *(const f16x8*)&pp[(size_t)j * BD];
    for (int g = 0; g < CHL / 4; ++g) {
        if (g + 1 < CHL / 4) {
#pragma unroll
            for (int j = 0; j < 4; ++j)
                nxt[j] = *(const f16x8*)&pp[(size_t)((g + 1) * 4 + j) * BD];
        }
#pragma unroll
        for (int j = 0; j < 4; ++j)
#pragma unroll
            for (int e = 0; e < 8; ++e)
                stepAB((float)cur[j][e], A[e], B[e]);
#pragma unroll
        for (int j = 0; j < 4; ++j) cur[j] = nxt[j];
    }
    float* ap = Ac + (size_t)c * BD + (size_t)q * 8;
    float* bp = Bc + (size_t)c * BD + (size_t)q * 8;
    *(float4*)&ap[0] = make_float4(A[0], A[1], A[2], A[3]);
    *(float4*)&ap[4] = make_float4(A[4], A[5], A[6], A[7]);
    *(float4*)&bp[0] = make_float4(B[0], B[1], B[2], B[3]);
    *(float4*)&bp[4] = make_float4(B[4], B[5], B[6], B[7]);
}

// ---------- Scan pass 2 (f16 proj in ws -> f32 out + h) ----------
__global__ __launch_bounds__(256) void scan_pass2h(const ushort* __restrict__ po,
                                                   const float* __restrict__ Ac,
                                                   const float* __restrict__ Bc,
                                                   float* __restrict__ out,
                                                   float* __restrict__ h_out) {
    const int blk = (int)blockIdx.x;         // 256 = 32 chunks x 8
    const int c   = blk >> 3;
    const int q   = (blk & 7) * 256 + (int)threadIdx.x;

    float h[8];
#pragma unroll
    for (int e = 0; e < 8; ++e) h[e] = 0.f;
    for (int j = 0; j < c; ++j) {
        const float* ap = Ac + (size_t)j * BD + (size_t)q * 8;
        const float* bp = Bc + (size_t)j * BD + (size_t)q * 8;
        const float4 a0 = *(const float4*)&ap[0], a1 = *(const float4*)&ap[4];
        const float4 b0 = *(const float4*)&bp[0], b1 = *(const float4*)&bp[4];
        h[0] = fmaf(a0.x, h[0], b0.x); h[1] = fmaf(a0.y, h[1], b0.y);
        h[2] = fmaf(a0.z, h[2], b0.z); h[3] = fmaf(a0.w, h[3], b0.w);
        h[4] = fmaf(a1.x, h[4], b1.x); h[5] = fmaf(a1.y, h[5], b1.y);
        h[6] = fmaf(a1.z, h[6], b1.z); h[7] = fmaf(a1.w, h[7], b1.w);
    }
    if (c == 0) {
        *(float4*)&h_out[(size_t)q * 8]     = make_float4(0.f, 0.f, 0.f, 0.f);
        *(float4*)&h_out[(size_t)q * 8 + 4] = make_float4(0.f, 0.f, 0.f, 0.f);
    }

    const ushort* pp = po + (size_t)c * CHL * BD + (size_t)q * 8;
    float* op = out   + (size_t)c * CHL * BD + (size_t)q * 8;
    float* hp = h_out + (size_t)c * CHL * BD + (size_t)q * 8 + BD;   // h[t+1]

    f16x8 cur[4], nxt[4];
#pragma unroll
    for (int j = 0; j < 4; ++j) cur[j] = *(const f16x8*)&pp[(size_t)j * BD];
    for (int g = 0; g < CHL / 4; ++g) {
        if (g + 1 < CHL / 4) {
#pragma unroll
            for (int j = 0; j < 4; ++j)
                nxt[j] = *(const f16x8*)&pp[(size_t)((g + 1) * 4 + j) * BD];
        }
#pragma unroll
        for (int j = 0; j < 4; ++j) {
            const size_t so = (size_t)(g * 4 + j) * BD;
            float o[8];
#pragma unroll
            for (int e = 0; e < 8; ++e) {
                stepH((float)cur[j][e], h[e]);
                o[e] = outOf(h[e]);
            }
            *(float4*)&op[so]     = make_float4(o[0], o[1], o[2], o[3]);
            *(float4*)&op[so + 4] = make_float4(o[4], o[5], o[6], o[7]);
            *(float4*)&hp[so]     = make_float4(h[0], h[1], h[2], h[3]);
            *(float4*)&hp[so + 4] = make_float4(h[4], h[5], h[6], h[7]);
        }
#pragma unroll
        for (int j = 0; j < 4; ++j) cur[j] = nxt[j];
    }
}

// ---------- legacy f32-proj scan passes (fallback if ws is small) ----------
__global__ __launch_bounds__(256) void scan_pass1(const float* __restrict__ po,
                                                  float4* __restrict__ Ac,
                                                  float4* __restrict__ Bc) {
    const int blk = (int)blockIdx.x;         // 496 = 31 x 16
    const int c   = blk >> 4;
    const int q   = (blk & 15) * 256 + (int)threadIdx.x;
    const float* pp = po + (size_t)c * CHL * BD + (size_t)q * 4;

    float4 A = make_float4(1.f, 1.f, 1.f, 1.f);
    float4 B = make_float4(0.f, 0.f, 0.f, 0.f);
    float4 cur[4], nxt[4];
#pragma unroll
    for (int j = 0; j < 4; ++j) cur[j] = *(const float4*)&pp[(size_t)j * BD];
    for (int g = 0; g < CHL / 4; ++g) {
        if (g + 1 < CHL / 4) {
#pragma unroll
            for (int j = 0; j < 4; ++j)
                nxt[j] = *(const float4*)&pp[(size_t)((g + 1) * 4 + j) * BD];
        }
#pragma unroll
        for (int j = 0; j < 4; ++j) {
            stepAB(cur[j].x, A.x, B.x);
            stepAB(cur[j].y, A.y, B.y);
            stepAB(cur[j].z, A.z, B.z);
            stepAB(cur[j].w, A.w, B.w);
        }
#pragma unroll
        for (int j = 0; j < 4; ++j) cur[j] = nxt[j];
    }
    Ac[c * NQ + q] = A;
    Bc[c * NQ + q] = B;
}

__global__ __launch_bounds__(256) void scan_pass2(float* __restrict__ po,
                                                  const float4* __restrict__ Ac,
                                                  const float4* __restrict__ Bc,
                                                  float* __restrict__ h_out) {
    const int blk = (int)blockIdx.x;         // 512 = 32 x 16
    const int c   = blk >> 4;
    const int q   = (blk & 15) * 256 + (int)threadIdx.x;

    float4 h = make_float4(0.f, 0.f, 0.f, 0.f);
    for (int j = 0; j < c; ++j) {
        const float4 A = Ac[j * NQ + q];
        const float4 B = Bc[j * NQ + q];
        h.x = fmaf(A.x, h.x, B.x);
        h.y = fmaf(A.y, h.y, B.y);
        h.z = fmaf(A.z, h.z, B.z);
        h.w = fmaf(A.w, h.w, B.w);
    }
    if (c == 0) *(float4*)&h_out[(size_t)q * 4] = make_float4(0.f, 0.f, 0.f, 0.f);

    float* pp = po + (size_t)c * CHL * BD + (size_t)q * 4;
    float* hp = h_out + (size_t)c * CHL * BD + (size_t)q * 4 + BD;

    float4 cur[4], nxt[4];
#pragma unroll
    for (int j = 0; j < 4; ++j) cur[j] = *(const float4*)&pp[(size_t)j * BD];
    for (int g = 0; g < CHL / 4; ++g) {
        if (g + 1 < CHL / 4) {
#pragma unroll
            for (int j = 0; j < 4; ++j)
                nxt[j] = *(const float4*)&pp[(size_t)((g + 1) * 4 + j) * BD];
        }
#pragma unroll
        for (int j = 0; j < 4; ++j) {
            const size_t so = (size_t)(g * 4 + j) * BD;
            stepH(cur[j].x, h.x);
            stepH(cur[j].y, h.y);
            stepH(cur[j].z, h.z);
            stepH(cur[j].w, h.w);
            float4 o;
            o.x = outOf(h.x); o.y = outOf(h.y); o.z = outOf(h.z); o.w = outOf(h.w);
            *(float4*)&pp[so] = o;
            *(float4*)&hp[so] = h;
        }
#pragma unroll
        for (int j = 0; j < 4; ++j) cur[j] = nxt[j];
    }
}

// ---------- last-resort sequential scan ----------
__global__ __launch_bounds__(64) void scan_fused(float* __restrict__ po,
                                                 float* __restrict__ h_out) {
    const int idx = (int)blockIdx.x * 64 + (int)threadIdx.x;
    float h = 0.f;
    h_out[idx] = 0.f;
    size_t off = (size_t)idx;
#pragma unroll 4
    for (int t = 0; t < T_DIM; ++t) {
        float p = po[off];
        stepH(p, h);
        po[off] = outOf(h);
        h_out[off + BD] = h;
        off += BD;
    }
}

extern "C" void kernel_launch(void* const* d_in, const int* in_sizes, int n_in,
                              void* d_out, int out_size, void* d_ws, size_t ws_size,
                              hipStream_t stream) {
    const float* x = (const float*)d_in[0];
    const float* W = (const float*)d_in[1];
    const float* b = (const float*)d_in[2];
    float* out = (float*)d_out;                                // outputs (128 MB)
    float* h   = out + (size_t)T_DIM * B_DIM * D_DIM;          // h region (134.2 MB)

    // Xf/Wh scratch in the h region (dead before pass2 writes h):
    ushort* Xf = (ushort*)h;                                   // 64 MB
    ushort* Wh = Xf + (size_t)M_DIM * K_DIM;                   // 2 MB

    convert_x<<<4096, 256, 0, stream>>>(x, Xf);
    convert_w<<<128, 256, 0, stream>>>(W, Wh);

    const size_t P16_BYTES = (size_t)M_DIM * N_DIM * 2;        // 64 MB
    const size_t AB_BYTES  = (size_t)NCH * BD * 4;             // 2 MB each

    if (ws_size >= P16_BYTES + 2 * AB_BYTES) {
        // f16 proj in workspace: half the proj write + both scan reads.
        ushort* P16 = (ushort*)d_ws;
        float*  Ac  = (float*)((char*)d_ws + P16_BYTES);
        float*  Bc  = Ac + (size_t)NCH * BD;
        gemm_proj<1><<<2048, 256, 0, stream>>>(Xf, Wh, b, nullptr, P16);
        scan_pass1h<<<(NCH - 1) * 8, 256, 0, stream>>>(P16, Ac, Bc);
        scan_pass2h<<<NCH * 8, 256, 0, stream>>>(P16, Ac, Bc, out, h);
    } else if (ws_size >= (size_t)4 * 1024 * 1024) {
        float4* Ac = (float4*)d_ws;
        float4* Bc = Ac + (size_t)NCH * NQ;
        gemm_proj<0><<<2048, 256, 0, stream>>>(Xf, Wh, b, out, nullptr);
        scan_pass1<<<(NCH - 1) * 16, 256, 0, stream>>>(out, Ac, Bc);
        scan_pass2<<<NCH * 16, 256, 0, stream>>>(out, Ac, Bc, h);
    } else {
        gemm_proj<0><<<2048, 256, 0, stream>>>(Xf, Wh, b, out, nullptr);
        scan_fused<<<BD / 64, 64, 0, stream>>>(out, h);
    }
}